// Round 6
// baseline (363.500 us; speedup 1.0000x reference)
//
#include <hip/hip_runtime.h>

// WeightedGCN: 2-layer GCNConv (PyG), N=100K, E=1.25M, D=64, fp32 in/out.
// R6: aggregates were wave-lifetime bound (~4-5 dependent memory phases x ~900cy,
//     24 wave-rounds). New k_agg: 16-lane group owns a node (4 nodes/wave -> 6
//     rounds), CSR slab loaded in ONE coalesced instr + shfl broadcast, all <=16
//     row-gathers in flight before a single wait, epilogue prefetched.
//     GEMM-2 fused into agg1 epilogue via LDS (kills the 51 MB Y round-trip).
// Build (R5 counting sort, zero per-edge global atomics) unchanged.

typedef unsigned int u32;
typedef unsigned short u16;

#define NBKT 1024        // coarse buckets
#define LSH 7            // 128 nodes per bucket
#define SRCBITS 17       // N=100K < 2^17

__device__ inline u16 f2bf(float f) {            // RNE fp32->bf16
  u32 u = __float_as_uint(f);
  u32 r = u + 0x7FFFu + ((u >> 16) & 1u);
  return (u16)(r >> 16);
}
__device__ inline float bf_lo(u32 p) { return __uint_as_float(p << 16); }
__device__ inline float bf_hi(u32 p) { return __uint_as_float(p & 0xFFFF0000u); }

// exclusive Hillis-Steele scan over 128 entries (256-thread block).
__device__ inline u32 scan128_excl(u32* sa, u32* sb, int tid, u32 val) {
  if (tid < 128) sa[tid] = val;
  __syncthreads();
  u32* s = sa; u32* d = sb;
  for (int st = 1; st < 128; st <<= 1) {
    if (tid < 128) d[tid] = s[tid] + (tid >= st ? s[tid - st] : 0u);
    __syncthreads();
    u32* t = s; s = d; d = t;
  }
  u32 incl = (tid < 128) ? s[tid] : 0u;
  return incl - val;
}

// ---- build pass 1: per-block bucket histogram (LDS atomics only) ----
__global__ void k_bin(const int* __restrict__ ei, u32* __restrict__ blockcnt,
                      int E, int chunk) {
  __shared__ u32 hist[NBKT];
  for (int i = threadIdx.x; i < NBKT; i += 256) hist[i] = 0u;
  __syncthreads();
  int e0 = blockIdx.x * chunk;
  int e1 = min(E, e0 + chunk);
  for (int e = e0 + threadIdx.x; e < e1; e += 256)
    atomicAdd(&hist[ei[E + e] >> LSH], 1u);
  __syncthreads();
  for (int i = threadIdx.x; i < NBKT; i += 256)
    blockcnt[i * 256 + blockIdx.x] = hist[i];
}

// ---- build pass 2a: exclusive scan of each bucket row (one wave/row) ----
__global__ void k_scan_rows(u32* __restrict__ blockcnt, u32* __restrict__ bucket_total) {
  int wid = blockIdx.x * 4 + (threadIdx.x >> 6);
  int lane = threadIdx.x & 63;
  u32* row = blockcnt + (size_t)wid * 256;
  uint4 v = ((uint4*)row)[lane];
  u32 s = v.x + v.y + v.z + v.w;
  u32 inc = s;
  #pragma unroll
  for (int d = 1; d < 64; d <<= 1) {
    u32 t = __shfl_up(inc, d);
    if (lane >= d) inc += t;
  }
  u32 excl = inc - s;
  uint4 o;
  o.x = excl; o.y = excl + v.x; o.z = o.y + v.y; o.w = o.z + v.z;
  ((uint4*)row)[lane] = o;
  if (lane == 63) bucket_total[wid] = inc;
}

// ---- build pass 2b: exclusive scan over 1024 bucket totals ----
__global__ void k_scan_buckets(const u32* __restrict__ bucket_total,
                               u32* __restrict__ bucket_start) {
  __shared__ u32 a[NBKT], b[NBKT];
  int t = threadIdx.x;                              // 1024 threads
  a[t] = bucket_total[t];
  __syncthreads();
  u32* s = a; u32* d = b;
  for (int st = 1; st < NBKT; st <<= 1) {
    d[t] = s[t] + (t >= st ? s[t - st] : 0u);
    __syncthreads();
    u32* tmp = s; s = d; d = tmp;
  }
  bucket_start[t + 1] = s[t];
  if (t == 0) bucket_start[0] = 0u;
}

// ---- build pass 3 (+ fused GEMM-1): scatter edges into bucket regions ----
__global__ void k_scatter_gemm(const int* __restrict__ ei, const float* __restrict__ w,
                               const u32* __restrict__ blockcnt, const u32* __restrict__ bucket_start,
                               uint2* __restrict__ bucketed,
                               const float* __restrict__ X, const float* __restrict__ W,
                               u16* __restrict__ H, int N, int E, int chunk) {
  __shared__ float Wt[64 * 65];                     // aliased by scatter cursors
  int tid = threadIdx.x;
  if ((int)blockIdx.x < 256) {
    u32* base = (u32*)Wt;
    for (int i = tid; i < NBKT; i += 256)
      base[i] = blockcnt[(size_t)i * 256 + blockIdx.x] + bucket_start[i];
    __syncthreads();
    int e0 = blockIdx.x * chunk, e1 = min(E, e0 + chunk);
    for (int e = e0 + tid; e < e1; e += 256) {
      int s = ei[e];
      int d = ei[E + e];
      float wv = w[e];
      u32 pos = atomicAdd(&base[d >> LSH], 1u);
      bucketed[pos] = make_uint2((u32)s | ((u32)(d & 127) << SRCBITS), __float_as_uint(wv));
    }
    return;
  }
  // GEMM branch: H1 = X @ W1^T -> bf16
  for (int i = tid; i < 4096; i += 256) Wt[(i & 63) * 65 + (i >> 6)] = W[i];
  __syncthreads();
  int lane = tid & 63, wv4 = tid >> 6;
  int row0 = ((int)blockIdx.x - 256) * 16 + wv4 * 4;
  if (row0 >= N) return;
  if (row0 + 3 < N) {
    const float4* x0 = (const float4*)(X + (size_t)row0 * 64);
    float a0 = 0.f, a1 = 0.f, a2 = 0.f, a3 = 0.f;
    #pragma unroll
    for (int k4 = 0; k4 < 16; ++k4) {
      float4 xa = x0[k4];
      float4 xb = x0[16 + k4];
      float4 xc = x0[32 + k4];
      float4 xd = x0[48 + k4];
      int k = k4 << 2;
      float w0 = Wt[k * 65 + lane], w1 = Wt[(k + 1) * 65 + lane];
      float w2 = Wt[(k + 2) * 65 + lane], w3 = Wt[(k + 3) * 65 + lane];
      a0 = fmaf(xa.x, w0, fmaf(xa.y, w1, fmaf(xa.z, w2, fmaf(xa.w, w3, a0))));
      a1 = fmaf(xb.x, w0, fmaf(xb.y, w1, fmaf(xb.z, w2, fmaf(xb.w, w3, a1))));
      a2 = fmaf(xc.x, w0, fmaf(xc.y, w1, fmaf(xc.z, w2, fmaf(xc.w, w3, a2))));
      a3 = fmaf(xd.x, w0, fmaf(xd.y, w1, fmaf(xd.z, w2, fmaf(xd.w, w3, a3))));
    }
    H[(size_t)row0 * 64 + lane]       = f2bf(a0);
    H[(size_t)(row0 + 1) * 64 + lane] = f2bf(a1);
    H[(size_t)(row0 + 2) * 64 + lane] = f2bf(a2);
    H[(size_t)(row0 + 3) * 64 + lane] = f2bf(a3);
  } else {
    const float* x0 = X + (size_t)row0 * 64;
    for (int r = 0; r < 4 && row0 + r < N; ++r) {
      float a = 0.f;
      for (int k = 0; k < 64; ++k) a = fmaf(x0[r * 64 + k], Wt[k * 65 + lane], a);
      H[(size_t)(row0 + r) * 64 + lane] = f2bf(a);
    }
  }
}

// ---- build pass 4: per-bucket node stats (packed LDS histogram) ----
__global__ void k_bucket_stats(const uint2* __restrict__ bucketed,
                               const u32* __restrict__ bucket_start,
                               float* __restrict__ dis, int* __restrict__ cnt,
                               int* __restrict__ startv, int N) {
  __shared__ u32 hist[128], sa[128], sb[128];
  int b = blockIdx.x, tid = threadIdx.x;
  if (tid < 128) hist[tid] = 0u;
  __syncthreads();
  u32 s0 = bucket_start[b], s1 = bucket_start[b + 1];
  for (u32 p = s0 + tid; p < s1; p += 256) {
    uint2 ed = bucketed[p];
    u32 local = (ed.x >> SRCBITS) & 127u;
    u32 wfix = (u32)(__uint_as_float(ed.y) * 262144.0f);   // 18 frac bits
    atomicAdd(&hist[local], (1u << 24) | wfix);
  }
  __syncthreads();
  u32 h = (tid < 128) ? hist[tid] : 0u;
  u32 c = h >> 24;
  u32 excl = scan128_excl(sa, sb, tid, c);
  int node = b * 128 + tid;
  if (tid < 128 && node < N) {
    float wsum = (float)(h & 0xFFFFFFu) * (1.0f / 262144.0f);
    dis[node] = rsqrtf(1.0f + wsum);            // deg >= 1 (self-loop)
    cnt[node] = (int)c;
    startv[node] = (int)(s0 + excl);
  }
}

// ---- build pass 5: final CSR {src, coef} via LDS cursors ----
__global__ void k_bucket_fill(const uint2* __restrict__ bucketed,
                              const u32* __restrict__ bucket_start,
                              const float* __restrict__ dis, const int* __restrict__ cnt,
                              int2* __restrict__ csr, int N) {
  __shared__ u32 cur[128], sa[128], sb[128];
  __shared__ float dloc[128];
  int b = blockIdx.x, tid = threadIdx.x;
  u32 s0 = bucket_start[b], s1 = bucket_start[b + 1];
  int node = b * 128 + tid;
  u32 c = 0;
  if (tid < 128) {
    c = (node < N) ? (u32)cnt[node] : 0u;
    dloc[tid] = (node < N) ? dis[node] : 0.f;
  }
  u32 excl = scan128_excl(sa, sb, tid, c);
  if (tid < 128) cur[tid] = excl;
  __syncthreads();
  for (u32 p = s0 + tid; p < s1; p += 256) {
    uint2 ed = bucketed[p];
    u32 src = ed.x & ((1u << SRCBITS) - 1u);
    u32 local = (ed.x >> SRCBITS) & 127u;
    float coef = dis[src] * __uint_as_float(ed.y) * dloc[local];
    u32 pos = atomicAdd(&cur[local], 1u);
    csr[s0 + pos] = make_int2((int)src, __float_as_int(coef));
  }
}

// ---- aggregate: 16-lane group per node, 16 nodes/block. FUSE: +b1,ReLU, x W2^T
// in LDS -> H2 (bf16). Non-FUSE: +b2 -> Y (fp32).
template <int FUSE>
__global__ __launch_bounds__(256) void k_agg(
    const u16* __restrict__ H, const float* __restrict__ dis,
    const int* __restrict__ startv, const int* __restrict__ cnt,
    const int2* __restrict__ csr, const float* __restrict__ bias,
    const float* __restrict__ W2, u16* __restrict__ H2,
    float* __restrict__ Y, int N) {
  __shared__ float W2t[64 * 65];
  __shared__ float accs[16][68];
  int tid = threadIdx.x;
  if (FUSE) {
    for (int i = tid; i < 4096; i += 256) W2t[(i & 63) * 65 + (i >> 6)] = W2[i];
  }
  int g = tid >> 4, gl = tid & 15, lane = tid & 63;
  int node = blockIdx.x * 16 + g;
  int fid = gl << 2;
  float4 acc = make_float4(0.f, 0.f, 0.f, 0.f);
  if (node < N) {
    int s0 = startv[node];
    int n = cnt[node];
    float d = dis[node];                                     // prefetch epilogue operands
    uint2 hs = *(const uint2*)(H + (size_t)node * 64 + fid);
    float4 b4 = *(const float4*)(bias + fid);
    for (int base = 0; base < n; base += 16) {
      int m = n - base; if (m > 16) m = 16;
      int2 ce = csr[s0 + base + (gl < m ? gl : m - 1)];      // 1 coalesced slab load
      uint2 hv[16];
      #pragma unroll
      for (int j = 0; j < 16; ++j) {                         // all gathers in flight
        int srcLane = (lane & 48) + j;
        int sj = __shfl(ce.x, srcLane);
        if (j < m) hv[j] = *(const uint2*)(H + (size_t)sj * 64 + fid);
      }
      #pragma unroll
      for (int j = 0; j < 16; ++j) {
        if (j < m) {
          float c = __int_as_float(__shfl(ce.y, (lane & 48) + j));
          acc.x = fmaf(bf_lo(hv[j].x), c, acc.x);
          acc.y = fmaf(bf_hi(hv[j].x), c, acc.y);
          acc.z = fmaf(bf_lo(hv[j].y), c, acc.z);
          acc.w = fmaf(bf_hi(hv[j].y), c, acc.w);
        }
      }
    }
    float dd = d * d;
    acc.x = fmaf(bf_lo(hs.x), dd, acc.x) + b4.x;
    acc.y = fmaf(bf_hi(hs.x), dd, acc.y) + b4.y;
    acc.z = fmaf(bf_lo(hs.y), dd, acc.z) + b4.z;
    acc.w = fmaf(bf_hi(hs.y), dd, acc.w) + b4.w;
    if (FUSE) {
      acc.x = fmaxf(acc.x, 0.f); acc.y = fmaxf(acc.y, 0.f);
      acc.z = fmaxf(acc.z, 0.f); acc.w = fmaxf(acc.w, 0.f);
    } else {
      *(float4*)(Y + (size_t)node * 64 + fid) = acc;
    }
  }
  if (FUSE) {
    *(float4*)&accs[g][fid] = (node < N) ? acc : make_float4(0.f, 0.f, 0.f, 0.f);
    __syncthreads();
    int wv = tid >> 6;
    float o0 = 0.f, o1 = 0.f, o2 = 0.f, o3 = 0.f;
    #pragma unroll
    for (int k4 = 0; k4 < 16; ++k4) {
      int k = k4 << 2;
      float4 a0 = *(const float4*)&accs[wv * 4 + 0][k];
      float4 a1 = *(const float4*)&accs[wv * 4 + 1][k];
      float4 a2 = *(const float4*)&accs[wv * 4 + 2][k];
      float4 a3 = *(const float4*)&accs[wv * 4 + 3][k];
      float w0 = W2t[k * 65 + lane], w1 = W2t[(k + 1) * 65 + lane];
      float w2 = W2t[(k + 2) * 65 + lane], w3 = W2t[(k + 3) * 65 + lane];
      o0 = fmaf(a0.x, w0, fmaf(a0.y, w1, fmaf(a0.z, w2, fmaf(a0.w, w3, o0))));
      o1 = fmaf(a1.x, w0, fmaf(a1.y, w1, fmaf(a1.z, w2, fmaf(a1.w, w3, o1))));
      o2 = fmaf(a2.x, w0, fmaf(a2.y, w1, fmaf(a2.z, w2, fmaf(a2.w, w3, o2))));
      o3 = fmaf(a3.x, w0, fmaf(a3.y, w1, fmaf(a3.z, w2, fmaf(a3.w, w3, o3))));
    }
    int n0 = blockIdx.x * 16 + wv * 4;
    if (n0 < N)     H2[(size_t)n0 * 64 + lane]       = f2bf(o0);
    if (n0 + 1 < N) H2[(size_t)(n0 + 1) * 64 + lane] = f2bf(o1);
    if (n0 + 2 < N) H2[(size_t)(n0 + 2) * 64 + lane] = f2bf(o2);
    if (n0 + 3 < N) H2[(size_t)(n0 + 3) * 64 + lane] = f2bf(o3);
  }
}

extern "C" void kernel_launch(void* const* d_in, const int* in_sizes, int n_in,
                              void* d_out, int out_size, void* d_ws, size_t ws_size,
                              hipStream_t stream) {
  const float* x  = (const float*)d_in[0];
  const int*   ei = (const int*)d_in[1];
  const float* w  = (const float*)d_in[2];
  const float* W1 = (const float*)d_in[3];
  const float* b1 = (const float*)d_in[4];
  const float* W2 = (const float*)d_in[5];
  const float* b2 = (const float*)d_in[6];
  const int N = in_sizes[0] / 64;
  const int E = in_sizes[2];

  char* ws = (char*)d_ws;
  size_t off = 0;
  auto alloc = [&](size_t bytes) -> char* {
    char* p = ws + off;
    off = (off + bytes + 255) & ~(size_t)255;
    return p;
  };
  u32*   blockcnt     = (u32*)  alloc((size_t)NBKT * 256 * 4);
  u32*   bucket_total = (u32*)  alloc((size_t)NBKT * 4);
  u32*   bucket_start = (u32*)  alloc((size_t)(NBKT + 1) * 4);
  uint2* bucketed     = (uint2*)alloc((size_t)E * 8);
  int2*  csr          = (int2*) alloc((size_t)E * 8);
  float* dis          = (float*)alloc((size_t)N * 4);
  int*   cnt          = (int*)  alloc((size_t)N * 4);
  int*   startv       = (int*)  alloc((size_t)N * 4);
  u16*   h1           = (u16*)  alloc((size_t)N * 64 * 2);
  u16*   h2           = (u16*)  alloc((size_t)N * 64 * 2);

  const int chunk = (E + 255) / 256;
  const int nbG = (N + 15) / 16;
  const int nbB = (N + 127) >> LSH;

  k_bin<<<256, 256, 0, stream>>>(ei, blockcnt, E, chunk);
  k_scan_rows<<<256, 256, 0, stream>>>(blockcnt, bucket_total);
  k_scan_buckets<<<1, 1024, 0, stream>>>(bucket_total, bucket_start);
  k_scatter_gemm<<<256 + nbG, 256, 0, stream>>>(ei, w, blockcnt, bucket_start,
                                                bucketed, x, W1, h1, N, E, chunk);
  k_bucket_stats<<<nbB, 256, 0, stream>>>(bucketed, bucket_start, dis, cnt, startv, N);
  k_bucket_fill<<<nbB, 256, 0, stream>>>(bucketed, bucket_start, dis, cnt, csr, N);

  k_agg<1><<<(N + 15) / 16, 256, 0, stream>>>(h1, dis, startv, cnt, csr, b1, W2, h2,
                                              (float*)d_out, N);
  k_agg<0><<<(N + 15) / 16, 256, 0, stream>>>(h2, dis, startv, cnt, csr, b2, W2, h2,
                                              (float*)d_out, N);
}

// Round 7
// 316.426 us; speedup vs baseline: 1.1488x; 1.1488x over previous
//
#include <hip/hip_runtime.h>

// WeightedGCN: 2-layer GCNConv (PyG), N=100K, E=1.25M, D=64, fp32 in/out.
// R7: R6's 16-lane-group agg blew VGPR to 164 -> 11% occupancy -> 162us (latency
//     hiding collapsed). Revert to R5 shape (wave/node, 4 edge-groups x 16 lanes)
//     and add bounded ILP: unroll-4 clamped-index rounds (4 csr + 4 gathers in
//     flight/lane), packed int4 node meta (1 load), launch_bounds(256,6).
//     GEMM-2 fusion reverted (21KB LDS + slowest-node sync was a net loss).
// Build: R5 two-level counting sort, zero per-edge global atomics.

typedef unsigned int u32;
typedef unsigned short u16;

#define NBKT 1024        // coarse buckets
#define LSH 7            // 128 nodes per bucket
#define SRCBITS 17       // N=100K < 2^17

__device__ inline u16 f2bf(float f) {            // RNE fp32->bf16
  u32 u = __float_as_uint(f);
  u32 r = u + 0x7FFFu + ((u >> 16) & 1u);
  return (u16)(r >> 16);
}
__device__ inline float bf_lo(u32 p) { return __uint_as_float(p << 16); }
__device__ inline float bf_hi(u32 p) { return __uint_as_float(p & 0xFFFF0000u); }

// exclusive Hillis-Steele scan over 128 entries (256-thread block).
__device__ inline u32 scan128_excl(u32* sa, u32* sb, int tid, u32 val) {
  if (tid < 128) sa[tid] = val;
  __syncthreads();
  u32* s = sa; u32* d = sb;
  for (int st = 1; st < 128; st <<= 1) {
    if (tid < 128) d[tid] = s[tid] + (tid >= st ? s[tid - st] : 0u);
    __syncthreads();
    u32* t = s; s = d; d = t;
  }
  u32 incl = (tid < 128) ? s[tid] : 0u;
  return incl - val;
}

// ---- build pass 1: per-block bucket histogram (LDS atomics only) ----
__global__ void k_bin(const int* __restrict__ ei, u32* __restrict__ blockcnt,
                      int E, int chunk) {
  __shared__ u32 hist[NBKT];
  for (int i = threadIdx.x; i < NBKT; i += 256) hist[i] = 0u;
  __syncthreads();
  int e0 = blockIdx.x * chunk;
  int e1 = min(E, e0 + chunk);
  for (int e = e0 + threadIdx.x; e < e1; e += 256)
    atomicAdd(&hist[ei[E + e] >> LSH], 1u);
  __syncthreads();
  for (int i = threadIdx.x; i < NBKT; i += 256)
    blockcnt[i * 256 + blockIdx.x] = hist[i];
}

// ---- build pass 2a: exclusive scan of each bucket row (one wave/row) ----
__global__ void k_scan_rows(u32* __restrict__ blockcnt, u32* __restrict__ bucket_total) {
  int wid = blockIdx.x * 4 + (threadIdx.x >> 6);
  int lane = threadIdx.x & 63;
  u32* row = blockcnt + (size_t)wid * 256;
  uint4 v = ((uint4*)row)[lane];
  u32 s = v.x + v.y + v.z + v.w;
  u32 inc = s;
  #pragma unroll
  for (int d = 1; d < 64; d <<= 1) {
    u32 t = __shfl_up(inc, d);
    if (lane >= d) inc += t;
  }
  u32 excl = inc - s;
  uint4 o;
  o.x = excl; o.y = excl + v.x; o.z = o.y + v.y; o.w = o.z + v.z;
  ((uint4*)row)[lane] = o;
  if (lane == 63) bucket_total[wid] = inc;
}

// ---- build pass 2b: exclusive scan over 1024 bucket totals ----
__global__ void k_scan_buckets(const u32* __restrict__ bucket_total,
                               u32* __restrict__ bucket_start) {
  __shared__ u32 a[NBKT], b[NBKT];
  int t = threadIdx.x;                              // 1024 threads
  a[t] = bucket_total[t];
  __syncthreads();
  u32* s = a; u32* d = b;
  for (int st = 1; st < NBKT; st <<= 1) {
    d[t] = s[t] + (t >= st ? s[t - st] : 0u);
    __syncthreads();
    u32* tmp = s; s = d; d = tmp;
  }
  bucket_start[t + 1] = s[t];
  if (t == 0) bucket_start[0] = 0u;
}

// ---- build pass 3 (+ fused GEMM-1): scatter edges into bucket regions ----
__global__ void k_scatter_gemm(const int* __restrict__ ei, const float* __restrict__ w,
                               const u32* __restrict__ blockcnt, const u32* __restrict__ bucket_start,
                               uint2* __restrict__ bucketed,
                               const float* __restrict__ X, const float* __restrict__ W,
                               u16* __restrict__ H, int N, int E, int chunk) {
  __shared__ float Wt[64 * 65];                     // aliased by scatter cursors
  int tid = threadIdx.x;
  if ((int)blockIdx.x < 256) {
    u32* base = (u32*)Wt;
    for (int i = tid; i < NBKT; i += 256)
      base[i] = blockcnt[(size_t)i * 256 + blockIdx.x] + bucket_start[i];
    __syncthreads();
    int e0 = blockIdx.x * chunk, e1 = min(E, e0 + chunk);
    for (int e = e0 + tid; e < e1; e += 256) {
      int s = ei[e];
      int d = ei[E + e];
      float wv = w[e];
      u32 pos = atomicAdd(&base[d >> LSH], 1u);
      bucketed[pos] = make_uint2((u32)s | ((u32)(d & 127) << SRCBITS), __float_as_uint(wv));
    }
    return;
  }
  // GEMM branch: H1 = X @ W1^T -> bf16
  for (int i = tid; i < 4096; i += 256) Wt[(i & 63) * 65 + (i >> 6)] = W[i];
  __syncthreads();
  int lane = tid & 63, wv4 = tid >> 6;
  int row0 = ((int)blockIdx.x - 256) * 16 + wv4 * 4;
  if (row0 >= N) return;
  if (row0 + 3 < N) {
    const float4* x0 = (const float4*)(X + (size_t)row0 * 64);
    float a0 = 0.f, a1 = 0.f, a2 = 0.f, a3 = 0.f;
    #pragma unroll
    for (int k4 = 0; k4 < 16; ++k4) {
      float4 xa = x0[k4];
      float4 xb = x0[16 + k4];
      float4 xc = x0[32 + k4];
      float4 xd = x0[48 + k4];
      int k = k4 << 2;
      float w0 = Wt[k * 65 + lane], w1 = Wt[(k + 1) * 65 + lane];
      float w2 = Wt[(k + 2) * 65 + lane], w3 = Wt[(k + 3) * 65 + lane];
      a0 = fmaf(xa.x, w0, fmaf(xa.y, w1, fmaf(xa.z, w2, fmaf(xa.w, w3, a0))));
      a1 = fmaf(xb.x, w0, fmaf(xb.y, w1, fmaf(xb.z, w2, fmaf(xb.w, w3, a1))));
      a2 = fmaf(xc.x, w0, fmaf(xc.y, w1, fmaf(xc.z, w2, fmaf(xc.w, w3, a2))));
      a3 = fmaf(xd.x, w0, fmaf(xd.y, w1, fmaf(xd.z, w2, fmaf(xd.w, w3, a3))));
    }
    H[(size_t)row0 * 64 + lane]       = f2bf(a0);
    H[(size_t)(row0 + 1) * 64 + lane] = f2bf(a1);
    H[(size_t)(row0 + 2) * 64 + lane] = f2bf(a2);
    H[(size_t)(row0 + 3) * 64 + lane] = f2bf(a3);
  } else {
    const float* x0 = X + (size_t)row0 * 64;
    for (int r = 0; r < 4 && row0 + r < N; ++r) {
      float a = 0.f;
      for (int k = 0; k < 64; ++k) a = fmaf(x0[r * 64 + k], Wt[k * 65 + lane], a);
      H[(size_t)(row0 + r) * 64 + lane] = f2bf(a);
    }
  }
}

// ---- build pass 4: per-bucket node stats + packed int4 meta ----
__global__ void k_bucket_stats(const uint2* __restrict__ bucketed,
                               const u32* __restrict__ bucket_start,
                               float* __restrict__ dis, int* __restrict__ cnt,
                               int4* __restrict__ info, int N) {
  __shared__ u32 hist[128], sa[128], sb[128];
  int b = blockIdx.x, tid = threadIdx.x;
  if (tid < 128) hist[tid] = 0u;
  __syncthreads();
  u32 s0 = bucket_start[b], s1 = bucket_start[b + 1];
  for (u32 p = s0 + tid; p < s1; p += 256) {
    uint2 ed = bucketed[p];
    u32 local = (ed.x >> SRCBITS) & 127u;
    u32 wfix = (u32)(__uint_as_float(ed.y) * 262144.0f);   // 18 frac bits
    atomicAdd(&hist[local], (1u << 24) | wfix);
  }
  __syncthreads();
  u32 h = (tid < 128) ? hist[tid] : 0u;
  u32 c = h >> 24;
  u32 excl = scan128_excl(sa, sb, tid, c);
  int node = b * 128 + tid;
  if (tid < 128 && node < N) {
    float wsum = (float)(h & 0xFFFFFFu) * (1.0f / 262144.0f);
    float dv = rsqrtf(1.0f + wsum);             // deg >= 1 (self-loop)
    dis[node] = dv;
    cnt[node] = (int)c;
    info[node] = make_int4((int)(s0 + excl), (int)c, __float_as_int(dv), 0);
  }
}

// ---- build pass 5: final CSR {src, coef} via LDS cursors ----
__global__ void k_bucket_fill(const uint2* __restrict__ bucketed,
                              const u32* __restrict__ bucket_start,
                              const float* __restrict__ dis, const int* __restrict__ cnt,
                              int2* __restrict__ csr, int N) {
  __shared__ u32 cur[128], sa[128], sb[128];
  __shared__ float dloc[128];
  int b = blockIdx.x, tid = threadIdx.x;
  u32 s0 = bucket_start[b], s1 = bucket_start[b + 1];
  int node = b * 128 + tid;
  u32 c = 0;
  if (tid < 128) {
    c = (node < N) ? (u32)cnt[node] : 0u;
    dloc[tid] = (node < N) ? dis[node] : 0.f;
  }
  u32 excl = scan128_excl(sa, sb, tid, c);
  if (tid < 128) cur[tid] = excl;
  __syncthreads();
  for (u32 p = s0 + tid; p < s1; p += 256) {
    uint2 ed = bucketed[p];
    u32 src = ed.x & ((1u << SRCBITS) - 1u);
    u32 local = (ed.x >> SRCBITS) & 127u;
    float coef = dis[src] * __uint_as_float(ed.y) * dloc[local];
    u32 pos = atomicAdd(&cur[local], 1u);
    csr[s0 + pos] = make_int2((int)src, __float_as_int(coef));
  }
}

// ---- GEMM (layer 2): fp32 in, bf16 out ----
__global__ void k_gemm(const float* __restrict__ X, const float* __restrict__ W,
                       u16* __restrict__ H, int N) {
  __shared__ float Wt[64][65];
  int tid = threadIdx.x;
  #pragma unroll
  for (int i = tid; i < 4096; i += 256) Wt[i & 63][i >> 6] = W[i];
  __syncthreads();
  int lane = tid & 63, wv = tid >> 6;
  int row0 = blockIdx.x * 16 + wv * 4;
  if (row0 >= N) return;
  if (row0 + 3 < N) {
    const float4* x0 = (const float4*)(X + (size_t)row0 * 64);
    float a0 = 0.f, a1 = 0.f, a2 = 0.f, a3 = 0.f;
    #pragma unroll
    for (int k4 = 0; k4 < 16; ++k4) {
      float4 xa = x0[k4];
      float4 xb = x0[16 + k4];
      float4 xc = x0[32 + k4];
      float4 xd = x0[48 + k4];
      int k = k4 << 2;
      float w0 = Wt[k][lane], w1 = Wt[k + 1][lane], w2 = Wt[k + 2][lane], w3 = Wt[k + 3][lane];
      a0 = fmaf(xa.x, w0, fmaf(xa.y, w1, fmaf(xa.z, w2, fmaf(xa.w, w3, a0))));
      a1 = fmaf(xb.x, w0, fmaf(xb.y, w1, fmaf(xb.z, w2, fmaf(xb.w, w3, a1))));
      a2 = fmaf(xc.x, w0, fmaf(xc.y, w1, fmaf(xc.z, w2, fmaf(xc.w, w3, a2))));
      a3 = fmaf(xd.x, w0, fmaf(xd.y, w1, fmaf(xd.z, w2, fmaf(xd.w, w3, a3))));
    }
    H[(size_t)row0 * 64 + lane]       = f2bf(a0);
    H[(size_t)(row0 + 1) * 64 + lane] = f2bf(a1);
    H[(size_t)(row0 + 2) * 64 + lane] = f2bf(a2);
    H[(size_t)(row0 + 3) * 64 + lane] = f2bf(a3);
  } else {
    const float* x0 = X + (size_t)row0 * 64;
    for (int r = 0; r < 4 && row0 + r < N; ++r) {
      float a = 0.f;
      for (int k = 0; k < 64; ++k) a = fmaf(x0[r * 64 + k], Wt[k][lane], a);
      H[(size_t)(row0 + r) * 64 + lane] = f2bf(a);
    }
  }
}

// ---- aggregation: wave/node; 4 edge-groups x 16 lanes; unroll-4 clamped rounds;
//      packed int4 meta; bf16 gather; fp32 out ----
template <int RELU>
__global__ __launch_bounds__(256, 6) void k_aggregate(
    const u16* __restrict__ H, const int4* __restrict__ info,
    const int2* __restrict__ csr, const float* __restrict__ bias,
    float* __restrict__ Y, int N) {
  int node = blockIdx.x * 4 + (threadIdx.x >> 6);
  if (node >= N) return;
  int lane = threadIdx.x & 63;
  int eg = lane >> 4;
  int fid = (lane & 15) << 2;
  int4 nfo = info[node];
  int s0 = nfo.x, n = nfo.y;
  float d = __int_as_float(nfo.z);
  uint2 hs = *(const uint2*)(H + (size_t)node * 64 + fid);   // independent prefetches
  float4 b4 = *(const float4*)(bias + fid);
  float4 acc = make_float4(0.f, 0.f, 0.f, 0.f);
  int nm1 = n - 1;
  for (int base = 0; base < n; base += 16) {
    int p0 = base + eg;
    int q0 = min(p0, nm1), q1 = min(p0 + 4, nm1);
    int q2 = min(p0 + 8, nm1), q3 = min(p0 + 12, nm1);
    int2 c0 = csr[s0 + q0];                                  // 4 csr loads in flight
    int2 c1 = csr[s0 + q1];
    int2 c2 = csr[s0 + q2];
    int2 c3 = csr[s0 + q3];
    uint2 h0 = *(const uint2*)(H + (size_t)c0.x * 64 + fid); // 4 gathers in flight
    uint2 h1 = *(const uint2*)(H + (size_t)c1.x * 64 + fid);
    uint2 h2 = *(const uint2*)(H + (size_t)c2.x * 64 + fid);
    uint2 h3 = *(const uint2*)(H + (size_t)c3.x * 64 + fid);
    float f0 = (p0      < n) ? __int_as_float(c0.y) : 0.f;   // OOB -> coef 0
    float f1 = (p0 + 4  < n) ? __int_as_float(c1.y) : 0.f;
    float f2 = (p0 + 8  < n) ? __int_as_float(c2.y) : 0.f;
    float f3 = (p0 + 12 < n) ? __int_as_float(c3.y) : 0.f;
    acc.x = fmaf(bf_lo(h0.x), f0, acc.x); acc.y = fmaf(bf_hi(h0.x), f0, acc.y);
    acc.z = fmaf(bf_lo(h0.y), f0, acc.z); acc.w = fmaf(bf_hi(h0.y), f0, acc.w);
    acc.x = fmaf(bf_lo(h1.x), f1, acc.x); acc.y = fmaf(bf_hi(h1.x), f1, acc.y);
    acc.z = fmaf(bf_lo(h1.y), f1, acc.z); acc.w = fmaf(bf_hi(h1.y), f1, acc.w);
    acc.x = fmaf(bf_lo(h2.x), f2, acc.x); acc.y = fmaf(bf_hi(h2.x), f2, acc.y);
    acc.z = fmaf(bf_lo(h2.y), f2, acc.z); acc.w = fmaf(bf_hi(h2.y), f2, acc.w);
    acc.x = fmaf(bf_lo(h3.x), f3, acc.x); acc.y = fmaf(bf_hi(h3.x), f3, acc.y);
    acc.z = fmaf(bf_lo(h3.y), f3, acc.z); acc.w = fmaf(bf_hi(h3.y), f3, acc.w);
  }
  acc.x += __shfl_xor(acc.x, 16); acc.y += __shfl_xor(acc.y, 16);
  acc.z += __shfl_xor(acc.z, 16); acc.w += __shfl_xor(acc.w, 16);
  acc.x += __shfl_xor(acc.x, 32); acc.y += __shfl_xor(acc.y, 32);
  acc.z += __shfl_xor(acc.z, 32); acc.w += __shfl_xor(acc.w, 32);
  if (eg == 0) {
    float dd = d * d;
    acc.x = fmaf(bf_lo(hs.x), dd, acc.x) + b4.x;
    acc.y = fmaf(bf_hi(hs.x), dd, acc.y) + b4.y;
    acc.z = fmaf(bf_lo(hs.y), dd, acc.z) + b4.z;
    acc.w = fmaf(bf_hi(hs.y), dd, acc.w) + b4.w;
    if (RELU) {
      acc.x = fmaxf(acc.x, 0.f); acc.y = fmaxf(acc.y, 0.f);
      acc.z = fmaxf(acc.z, 0.f); acc.w = fmaxf(acc.w, 0.f);
    }
    *(float4*)(Y + (size_t)node * 64 + fid) = acc;
  }
}

extern "C" void kernel_launch(void* const* d_in, const int* in_sizes, int n_in,
                              void* d_out, int out_size, void* d_ws, size_t ws_size,
                              hipStream_t stream) {
  const float* x  = (const float*)d_in[0];
  const int*   ei = (const int*)d_in[1];
  const float* w  = (const float*)d_in[2];
  const float* W1 = (const float*)d_in[3];
  const float* b1 = (const float*)d_in[4];
  const float* W2 = (const float*)d_in[5];
  const float* b2 = (const float*)d_in[6];
  const int N = in_sizes[0] / 64;
  const int E = in_sizes[2];

  char* ws = (char*)d_ws;
  size_t off = 0;
  auto alloc = [&](size_t bytes) -> char* {
    char* p = ws + off;
    off = (off + bytes + 255) & ~(size_t)255;
    return p;
  };
  u32*   blockcnt     = (u32*)  alloc((size_t)NBKT * 256 * 4);
  u32*   bucket_total = (u32*)  alloc((size_t)NBKT * 4);
  u32*   bucket_start = (u32*)  alloc((size_t)(NBKT + 1) * 4);
  uint2* bucketed     = (uint2*)alloc((size_t)E * 8);
  int2*  csr          = (int2*) alloc((size_t)E * 8);
  float* dis          = (float*)alloc((size_t)N * 4);
  int*   cnt          = (int*)  alloc((size_t)N * 4);
  int4*  info         = (int4*) alloc((size_t)N * 16);
  u16*   h1           = (u16*)  alloc((size_t)N * 64 * 2);
  u16*   h2           = (u16*)  alloc((size_t)N * 64 * 2);
  float* ybuf         = (float*)d_out;             // layer-1 activations (fp32)

  const int chunk = (E + 255) / 256;
  const int nbG = (N + 15) / 16;
  const int nbB = (N + 127) >> LSH;

  k_bin<<<256, 256, 0, stream>>>(ei, blockcnt, E, chunk);
  k_scan_rows<<<256, 256, 0, stream>>>(blockcnt, bucket_total);
  k_scan_buckets<<<1, 1024, 0, stream>>>(bucket_total, bucket_start);
  k_scatter_gemm<<<256 + nbG, 256, 0, stream>>>(ei, w, blockcnt, bucket_start,
                                                bucketed, x, W1, h1, N, E, chunk);
  k_bucket_stats<<<nbB, 256, 0, stream>>>(bucketed, bucket_start, dis, cnt, info, N);
  k_bucket_fill<<<nbB, 256, 0, stream>>>(bucketed, bucket_start, dis, cnt, csr, N);

  k_aggregate<1><<<(N + 3) / 4, 256, 0, stream>>>(h1, info, csr, b1, ybuf, N);
  k_gemm<<<nbG, 256, 0, stream>>>(ybuf, W2, h2, N);
  k_aggregate<0><<<(N + 3) / 4, 256, 0, stream>>>(h2, info, csr, b2, (float*)d_out, N);
}